// Round 1
// baseline (739.909 us; speedup 1.0000x reference)
//
#include <hip/hip_runtime.h>
#include <hip/hip_bf16.h>
#include <cstddef>

// RSAGEConv: 2-layer hetero SAGE (mean agg), N=50000, R=3, E=600000, 128->256->128.
// fp32 in/out. CSR gather aggregation + bf16 MFMA GEMMs.
// Pipeline:
//  hist_prep (fused): hist atomics || {Abig[:,0:128]=bf16(x); B1t,B2t; bias sums}
//  scan -> add_offsets (bcur := 0)
//  bucket_scatter: bin edges by (r, dst>>6) into 2346 buckets; packed (dlow<<16|src)
//                  -> consecutive atomic returns hit consecutive slots so 64B lines
//                  merge in L2 (r6 fill had 121MB WRITE for 7.2MB payload: ~7us
//                  between same-line writes -> evicted every time; here ~0.8us)
//  bucket_sort:    per-bucket LDS counting sort (64 nodes) -> coalesced u16 col
//                  (replaces fill's per-node scatter AND compact)
//  gather1:   Abig[:,128+128r] = mean_r(bf16 x)   (unroll-8, u16 col)
//  gemm1m:    h = bf16(relu(Abig @ B1t^T + bias1))   [MFMA, K=512 -> 256]
//  gemm2m:    out(fp32) | y(bf16) = h @ B2t^T + bias2 [MFMA, K=256 -> 512]
//  gather2:   out[n] += sum_r mean_r(y)            (unroll-8, u16 col)
//
// Fill-scatter history (dur / WRITE_SIZE):
//   r6:  rowptr+cursor0, int col @0x200000          -> 90us / 121MB  (prev best)
//   r7/8: u16 scattered store                       -> 107-118us
//   r9:  nt int store                               -> 147us / 127MB
//   r10: preinit-cursor int store                   -> 135us / 112MB

#define NN 50000
#define RR 3
#define EE 600000
#define DIN 128
#define DHID 256
#define DOUT 128
#define NRN (RR * NN)

#define NPB 64                      // nodes per bucket
#define NBR ((NN + NPB - 1) / NPB)  // 782 buckets per relation
#define NBK (RR * NBR)              // 2346 buckets total
#define MAXB 1536                   // max edges per bucket (mean 768, ~27 sigma headroom)

typedef __hip_bfloat16 bf16;
typedef __hip_bfloat162 bf162;
typedef unsigned short u16;
typedef __attribute__((ext_vector_type(8))) short short8;
typedef __attribute__((ext_vector_type(4))) float floatx4;

__device__ __forceinline__ void async_copy16(const void* g, void* l) {
    __builtin_amdgcn_global_load_lds((const __attribute__((address_space(1))) void*)g,
                                     (__attribute__((address_space(3))) void*)l, 16, 0, 0);
}

// ---------------- fused hist + prep ----------------
#define HIST_BLOCKS ((RR * EE + 255) / 256)          // 7032
#define PREP_A (NN * 64)
#define PREP_B (256 * 512)
#define PREP_C (512 * 256)
#define PREP_D 384
#define PREP_TOTAL (PREP_A + PREP_B + PREP_C + PREP_D)
#define PREP_BLOCKS ((PREP_TOTAL + 255) / 256)

__global__ void hist_prep_kernel(const int* __restrict__ dst, int* __restrict__ hist,
        const float* __restrict__ x,
        const float* __restrict__ Ws1, const float* __restrict__ Wn1,
        const float* __restrict__ b1,
        const float* __restrict__ Ws2, const float* __restrict__ Wn2,
        const float* __restrict__ b2,
        bf16* __restrict__ Abig, bf16* __restrict__ B1t, bf16* __restrict__ B2t,
        float* __restrict__ bias1, float* __restrict__ bias2) {
    if (blockIdx.x < HIST_BLOCKS) {
        int e = blockIdx.x * 256 + threadIdx.x;
        if (e >= RR * EE) return;
        int r = e / EE;
        atomicAdd(&hist[r * NN + dst[e]], 1);
        return;
    }
    int idx = (blockIdx.x - HIST_BLOCKS) * 256 + threadIdx.x;
    if (idx < PREP_A) {
        int n = idx >> 6, c2 = idx & 63;
        float2 v = *(const float2*)&x[(size_t)n * DIN + c2 * 2];
        bf162 o; o.x = __float2bfloat16(v.x); o.y = __float2bfloat16(v.y);
        *(bf162*)&Abig[(size_t)n * 512 + c2 * 2] = o;
        return;
    }
    idx -= PREP_A;
    if (idx < PREP_B) {
        int n = idx >> 9, k = idx & 511;
        float v;
        if (k < 128) {
            v = Ws1[(size_t)k * 256 + n]
              + Ws1[(size_t)(128 + k) * 256 + n]
              + Ws1[(size_t)(256 + k) * 256 + n];
        } else {
            int q = k - 128; int r = q >> 7; int kk = q & 127;
            v = Wn1[((size_t)r * 128 + kk) * 256 + n];
        }
        B1t[(size_t)n * 512 + k] = __float2bfloat16(v);
        return;
    }
    idx -= PREP_B;
    if (idx < PREP_C) {
        int n = idx >> 8, k = idx & 255;
        float v;
        if (n < 128) {
            v = Ws2[(size_t)k * 128 + n]
              + Ws2[(size_t)(256 + k) * 128 + n]
              + Ws2[(size_t)(512 + k) * 128 + n];
        } else {
            int q = n - 128; int r = q >> 7; int nn = q & 127;
            v = Wn2[((size_t)r * 256 + k) * 128 + nn];
        }
        B2t[(size_t)n * 256 + k] = __float2bfloat16(v);
        return;
    }
    idx -= PREP_C;
    if (idx < PREP_D) {
        if (idx < 256) {
            bias1[idx] = b1[idx] + b1[256 + idx] + b1[512 + idx];
        } else {
            int j = idx - 256;
            bias2[j] = b2[j] + b2[128 + j] + b2[256 + j];
        }
    }
}

// ---------------- exclusive scan over NRN ints ----------------
__global__ __launch_bounds__(256) void scan_blocks(const int* __restrict__ in,
        int* __restrict__ out, int* __restrict__ bsums, int n) {
    int t = threadIdx.x;
    int base = blockIdx.x * 1024 + t * 4;
    int v[4];
    #pragma unroll
    for (int i = 0; i < 4; ++i) v[i] = (base + i < n) ? in[base + i] : 0;
    int s = v[0] + v[1] + v[2] + v[3];
    int lane = t & 63, wid = t >> 6;
    int sc = s;
    #pragma unroll
    for (int d = 1; d < 64; d <<= 1) {
        int tt = __shfl_up(sc, d, 64);
        if (lane >= d) sc += tt;
    }
    __shared__ int wsum[4], woff[4];
    if (lane == 63) wsum[wid] = sc;
    __syncthreads();
    if (t == 0) {
        int a = 0;
        #pragma unroll
        for (int i = 0; i < 4; ++i) { woff[i] = a; a += wsum[i]; }
    }
    __syncthreads();
    int run = sc - s + woff[wid];
    #pragma unroll
    for (int i = 0; i < 4; ++i) {
        if (base + i < n) out[base + i] = run;
        run += v[i];
    }
    if (t == 255) bsums[blockIdx.x] = woff[3] + wsum[3];
}

__global__ __launch_bounds__(256) void scan_sums(int* __restrict__ bsums, int nb) {
    int t = threadIdx.x;
    int v = (t < nb) ? bsums[t] : 0;
    int lane = t & 63, wid = t >> 6;
    int sc = v;
    #pragma unroll
    for (int d = 1; d < 64; d <<= 1) {
        int tt = __shfl_up(sc, d, 64);
        if (lane >= d) sc += tt;
    }
    __shared__ int wsum[4], woff[4];
    if (lane == 63) wsum[wid] = sc;
    __syncthreads();
    if (t == 0) {
        int a = 0;
        #pragma unroll
        for (int i = 0; i < 4; ++i) { woff[i] = a; a += wsum[i]; }
    }
    __syncthreads();
    if (t < nb) bsums[t] = sc - v + woff[wid];
}

// rowptr finalize + bucket cursors := 0
__global__ void add_offsets(int* __restrict__ rowptr, const int* __restrict__ bsums,
                            int* __restrict__ bcur, int n) {
    int i = blockIdx.x * 256 + threadIdx.x;
    if (i < n) rowptr[i] += bsums[i >> 10];
    if (i < NBK) bcur[i] = 0;
    if (i == 0) rowptr[n] = RR * EE;
}

// ---------------- pass 1: bin edges into 64-node buckets ----------------
// Bucket base comes from rowptr (buckets are node-aligned), so the binned array
// is exactly edge-count-sized. Consecutive atomic returns -> consecutive slots
// -> same-line writes are ~0.8us apart -> L2 merges them (vs r6's ~7us gaps).
__global__ void bucket_scatter(const int* __restrict__ src, const int* __restrict__ dst,
                               const int* __restrict__ rowptr, int* __restrict__ bcur,
                               unsigned* __restrict__ ebuf) {
    int e = blockIdx.x * 256 + threadIdx.x;
    if (e >= RR * EE) return;
    int r = e / EE;
    int d = dst[e];
    int b0 = d >> 6;                         // bucket within relation
    int base = rowptr[r * NN + (b0 << 6)];   // 2346 hot addresses (L2-resident)
    int pos = base + atomicAdd(&bcur[r * NBR + b0], 1);
    ebuf[pos] = ((unsigned)(d & 63) << 16) | (unsigned)src[e];
}

// ---------------- pass 2: per-bucket LDS counting sort -> coalesced u16 col ----------------
__global__ __launch_bounds__(256) void bucket_sort(const int* __restrict__ rowptr,
        const unsigned* __restrict__ ebuf, u16* __restrict__ col) {
    int b = blockIdx.x;                  // [0, NBK)
    int r = b / NBR;
    int b0 = b - r * NBR;
    int node0 = b0 * NPB;
    int gbase = r * NN + node0;
    int nn = min(NPB, NN - node0);
    int beg = rowptr[gbase];
    int end = rowptr[gbase + nn];
    int cnt = min(end - beg, MAXB);

    __shared__ unsigned eb[MAXB];
    __shared__ u16 sb[MAXB];
    __shared__ int lh[NPB];
    __shared__ int lc[NPB];

    for (int i = threadIdx.x; i < cnt; i += 256) eb[i] = ebuf[beg + i];
    if (threadIdx.x < NPB) lh[threadIdx.x] = 0;
    __syncthreads();
    for (int i = threadIdx.x; i < cnt; i += 256) atomicAdd(&lh[eb[i] >> 16], 1);
    __syncthreads();
    if (threadIdx.x < NPB) {              // wave 0: exclusive scan of 64 counters
        int v = lh[threadIdx.x];
        int sc = v;
        #pragma unroll
        for (int d = 1; d < 64; d <<= 1) {
            int tt = __shfl_up(sc, d, 64);
            if (threadIdx.x >= d) sc += tt;
        }
        lc[threadIdx.x] = sc - v;
    }
    __syncthreads();
    for (int i = threadIdx.x; i < cnt; i += 256) {
        unsigned e = eb[i];
        int pos = atomicAdd(&lc[e >> 16], 1);
        sb[pos] = (u16)(e & 0xffffu);
    }
    __syncthreads();
    for (int i = threadIdx.x; i < cnt; i += 256) col[beg + i] = sb[i];
}

__device__ __forceinline__ float bflo(unsigned u) { return __uint_as_float(u << 16); }
__device__ __forceinline__ float bfhi(unsigned u) { return __uint_as_float(u & 0xffff0000u); }

// ---------------- gather1: Abig[n][128+128r..] = mean_{s in col[r,n]} bf16x[s] ----------------
__global__ __launch_bounds__(256) void gather1(const int* __restrict__ rowptr,
        const u16* __restrict__ col, bf16* __restrict__ Abig) {
    int g = blockIdx.x * 4 + (threadIdx.x >> 6);   // r*NN + n
    int lane = threadIdx.x & 63;
    int r = g / NN;
    int n = g - r * NN;
    int beg = rowptr[g], end = rowptr[g + 1];
    const unsigned* xb = (const unsigned*)Abig;    // row stride 256 uints
    float acc0 = 0.f, acc1 = 0.f;
    for (int base = beg; base < end; base += 64) {
        int cnt = min(64, end - base);
        int cidx = (lane < cnt) ? (int)col[base + lane] : 0;
        int j = 0;
        for (; j + 8 <= cnt; j += 8) {
            unsigned u0 = xb[(size_t)__shfl(cidx, j,     64) * 256 + lane];
            unsigned u1 = xb[(size_t)__shfl(cidx, j + 1, 64) * 256 + lane];
            unsigned u2 = xb[(size_t)__shfl(cidx, j + 2, 64) * 256 + lane];
            unsigned u3 = xb[(size_t)__shfl(cidx, j + 3, 64) * 256 + lane];
            unsigned u4 = xb[(size_t)__shfl(cidx, j + 4, 64) * 256 + lane];
            unsigned u5 = xb[(size_t)__shfl(cidx, j + 5, 64) * 256 + lane];
            unsigned u6 = xb[(size_t)__shfl(cidx, j + 6, 64) * 256 + lane];
            unsigned u7 = xb[(size_t)__shfl(cidx, j + 7, 64) * 256 + lane];
            acc0 += bflo(u0) + bflo(u1) + bflo(u2) + bflo(u3)
                  + bflo(u4) + bflo(u5) + bflo(u6) + bflo(u7);
            acc1 += bfhi(u0) + bfhi(u1) + bfhi(u2) + bfhi(u3)
                  + bfhi(u4) + bfhi(u5) + bfhi(u6) + bfhi(u7);
        }
        for (; j + 4 <= cnt; j += 4) {
            unsigned u0 = xb[(size_t)__shfl(cidx, j,     64) * 256 + lane];
            unsigned u1 = xb[(size_t)__shfl(cidx, j + 1, 64) * 256 + lane];
            unsigned u2 = xb[(size_t)__shfl(cidx, j + 2, 64) * 256 + lane];
            unsigned u3 = xb[(size_t)__shfl(cidx, j + 3, 64) * 256 + lane];
            acc0 += bflo(u0) + bflo(u1) + bflo(u2) + bflo(u3);
            acc1 += bfhi(u0) + bfhi(u1) + bfhi(u2) + bfhi(u3);
        }
        for (; j < cnt; ++j) {
            unsigned u = xb[(size_t)__shfl(cidx, j, 64) * 256 + lane];
            acc0 += bflo(u);
            acc1 += bfhi(u);
        }
    }
    float inv = 1.0f / fmaxf((float)(end - beg), 1.0f);
    bf162 o;
    o.x = __float2bfloat16(acc0 * inv);
    o.y = __float2bfloat16(acc1 * inv);
    *(bf162*)&Abig[(size_t)n * 512 + 128 + r * 128 + lane * 2] = o;
}

// ---------------- MFMA GEMM 1: Abig[N][512](bf16) x B1t[256][512] -> h bf16 [N][256] ----------------
__global__ __launch_bounds__(256) void gemm1m(const bf16* __restrict__ A,
        const bf16* __restrict__ Bt, const float* __restrict__ bias1,
        bf16* __restrict__ h) {
    __shared__ short As[128 * 32];
    __shared__ short Bs[128 * 32];
    const int t = threadIdx.x;
    const int wv = t >> 6, lane = t & 63;
    const int wr = wv >> 1, wc = wv & 1;
    const int m16 = lane & 15, kg = lane >> 4;
    const int row0 = blockIdx.x * 128;
    const int col0 = blockIdx.y * 128;
    const int ldrow = (t >> 2);
    const int ldk = (t & 3) * 8;
    const int arow0 = min(row0 + ldrow, NN - 1);
    const int arow1 = min(row0 + ldrow + 64, NN - 1);
    const short* Ag0 = (const short*)A + (size_t)arow0 * 512 + ldk;
    const short* Ag1 = (const short*)A + (size_t)arow1 * 512 + ldk;
    const short* Bg = (const short*)Bt + (size_t)(col0 + ldrow) * 512 + ldk;
    short* AsW = &As[(size_t)wv * 512];
    short* BsW = &Bs[(size_t)wv * 512];

    floatx4 acc[4][4] = {};
    for (int kb = 0; kb < 512; kb += 32) {
        async_copy16(Ag0 + kb, AsW);
        async_copy16(Ag1 + kb, AsW + 2048);
        async_copy16(Bg + kb, BsW);
        async_copy16(Bg + kb + (size_t)64 * 512, BsW + 2048);
        __syncthreads();
        short8 a[4], b[4];
        #pragma unroll
        for (int i = 0; i < 4; ++i)
            a[i] = *(const short8*)&As[(wr * 64 + i * 16 + m16) * 32 + kg * 8];
        #pragma unroll
        for (int j = 0; j < 4; ++j)
            b[j] = *(const short8*)&Bs[(wc * 64 + j * 16 + m16) * 32 + kg * 8];
        #pragma unroll
        for (int i = 0; i < 4; ++i)
            #pragma unroll
            for (int j = 0; j < 4; ++j)
                acc[i][j] = __builtin_amdgcn_mfma_f32_16x16x32_bf16(a[i], b[j], acc[i][j], 0, 0, 0);
        __syncthreads();
    }
    #pragma unroll
    for (int j = 0; j < 4; ++j) {
        int c = col0 + wc * 64 + j * 16 + m16;
        float bj = bias1[c];
        #pragma unroll
        for (int i = 0; i < 4; ++i) {
            int rb = row0 + wr * 64 + i * 16 + kg * 4;
            #pragma unroll
            for (int reg = 0; reg < 4; ++reg) {
                int r = rb + reg;
                if (r < NN)
                    h[(size_t)r * DHID + c] = __float2bfloat16(fmaxf(acc[i][j][reg] + bj, 0.f));
            }
        }
    }
}

// ---------------- MFMA GEMM 2: h[N][256](bf16) x B2t[512][256] -> out fp32 [N][128] + y bf16 [3][N][128]
__global__ __launch_bounds__(256) void gemm2m(const bf16* __restrict__ A,
        const bf16* __restrict__ Bt, const float* __restrict__ bias2,
        float* __restrict__ out, bf16* __restrict__ y) {
    __shared__ short As[128 * 32];
    __shared__ short Bs[128 * 32];
    const int t = threadIdx.x;
    const int wv = t >> 6, lane = t & 63;
    const int wr = wv >> 1, wc = wv & 1;
    const int m16 = lane & 15, kg = lane >> 4;
    const int row0 = blockIdx.x * 128;
    const int col0 = blockIdx.y * 128;
    const int ldrow = (t >> 2);
    const int ldk = (t & 3) * 8;
    const int arow0 = min(row0 + ldrow, NN - 1);
    const int arow1 = min(row0 + ldrow + 64, NN - 1);
    const short* Ag0 = (const short*)A + (size_t)arow0 * 256 + ldk;
    const short* Ag1 = (const short*)A + (size_t)arow1 * 256 + ldk;
    const short* Bg = (const short*)Bt + (size_t)(col0 + ldrow) * 256 + ldk;
    short* AsW = &As[(size_t)wv * 512];
    short* BsW = &Bs[(size_t)wv * 512];

    floatx4 acc[4][4] = {};
    for (int kb = 0; kb < 256; kb += 32) {
        async_copy16(Ag0 + kb, AsW);
        async_copy16(Ag1 + kb, AsW + 2048);
        async_copy16(Bg + kb, BsW);
        async_copy16(Bg + kb + (size_t)64 * 256, BsW + 2048);
        __syncthreads();
        short8 a[4], b[4];
        #pragma unroll
        for (int i = 0; i < 4; ++i)
            a[i] = *(const short8*)&As[(wr * 64 + i * 16 + m16) * 32 + kg * 8];
        #pragma unroll
        for (int j = 0; j < 4; ++j)
            b[j] = *(const short8*)&Bs[(wc * 64 + j * 16 + m16) * 32 + kg * 8];
        #pragma unroll
        for (int i = 0; i < 4; ++i)
            #pragma unroll
            for (int j = 0; j < 4; ++j)
                acc[i][j] = __builtin_amdgcn_mfma_f32_16x16x32_bf16(a[i], b[j], acc[i][j], 0, 0, 0);
        __syncthreads();
    }
    if (blockIdx.y == 0) {
        #pragma unroll
        for (int j = 0; j < 4; ++j) {
            int c = wc * 64 + j * 16 + m16;
            float bj = bias2[c];
            #pragma unroll
            for (int i = 0; i < 4; ++i) {
                int rb = row0 + wr * 64 + i * 16 + kg * 4;
                #pragma unroll
                for (int reg = 0; reg < 4; ++reg) {
                    int r = rb + reg;
                    if (r < NN) out[(size_t)r * DOUT + c] = acc[i][j][reg] + bj;
                }
            }
        }
    } else {
        int rel = blockIdx.y - 1;
        bf16* yr = y + (size_t)rel * NN * DOUT;
        #pragma unroll
        for (int j = 0; j < 4; ++j) {
            int c = wc * 64 + j * 16 + m16;
            #pragma unroll
            for (int i = 0; i < 4; ++i) {
                int rb = row0 + wr * 64 + i * 16 + kg * 4;
                #pragma unroll
                for (int reg = 0; reg < 4; ++reg) {
                    int r = rb + reg;
                    if (r < NN) yr[(size_t)r * DOUT + c] = __float2bfloat16(acc[i][j][reg]);
                }
            }
        }
    }
}

// ---------------- gather2: out[n] += sum_r mean_{s in col[r,n]} y[r][s] (unroll-8) ----------------
__global__ __launch_bounds__(256) void gather2(const bf16* __restrict__ y,
        const int* __restrict__ rowptr, const u16* __restrict__ col,
        float* __restrict__ out) {
    int n = blockIdx.x * 4 + (threadIdx.x >> 6);
    int lane = threadIdx.x & 63;
    float2 acc = *(float2*)&out[(size_t)n * DOUT + lane * 2];
    const unsigned* yb = (const unsigned*)y;   // row stride 64 uints
    #pragma unroll
    for (int r = 0; r < RR; ++r) {
        const unsigned* ybr = yb + (size_t)r * NN * 64;
        int g = r * NN + n;
        int beg = rowptr[g], end = rowptr[g + 1];
        float a0 = 0.f, a1 = 0.f;
        for (int base = beg; base < end; base += 64) {
            int cnt = min(64, end - base);
            int cidx = (lane < cnt) ? (int)col[base + lane] : 0;
            int j = 0;
            for (; j + 8 <= cnt; j += 8) {
                unsigned u0 = ybr[(size_t)__shfl(cidx, j,     64) * 64 + lane];
                unsigned u1 = ybr[(size_t)__shfl(cidx, j + 1, 64) * 64 + lane];
                unsigned u2 = ybr[(size_t)__shfl(cidx, j + 2, 64) * 64 + lane];
                unsigned u3 = ybr[(size_t)__shfl(cidx, j + 3, 64) * 64 + lane];
                unsigned u4 = ybr[(size_t)__shfl(cidx, j + 4, 64) * 64 + lane];
                unsigned u5 = ybr[(size_t)__shfl(cidx, j + 5, 64) * 64 + lane];
                unsigned u6 = ybr[(size_t)__shfl(cidx, j + 6, 64) * 64 + lane];
                unsigned u7 = ybr[(size_t)__shfl(cidx, j + 7, 64) * 64 + lane];
                a0 += bflo(u0) + bflo(u1) + bflo(u2) + bflo(u3)
                    + bflo(u4) + bflo(u5) + bflo(u6) + bflo(u7);
                a1 += bfhi(u0) + bfhi(u1) + bfhi(u2) + bfhi(u3)
                    + bfhi(u4) + bfhi(u5) + bfhi(u6) + bfhi(u7);
            }
            for (; j + 4 <= cnt; j += 4) {
                unsigned u0 = ybr[(size_t)__shfl(cidx, j,     64) * 64 + lane];
                unsigned u1 = ybr[(size_t)__shfl(cidx, j + 1, 64) * 64 + lane];
                unsigned u2 = ybr[(size_t)__shfl(cidx, j + 2, 64) * 64 + lane];
                unsigned u3 = ybr[(size_t)__shfl(cidx, j + 3, 64) * 64 + lane];
                a0 += bflo(u0) + bflo(u1) + bflo(u2) + bflo(u3);
                a1 += bfhi(u0) + bfhi(u1) + bfhi(u2) + bfhi(u3);
            }
            for (; j < cnt; ++j) {
                unsigned u = ybr[(size_t)__shfl(cidx, j, 64) * 64 + lane];
                a0 += bflo(u);
                a1 += bfhi(u);
            }
        }
        float inv = 1.0f / fmaxf((float)(end - beg), 1.0f);
        acc.x += a0 * inv;
        acc.y += a1 * inv;
    }
    *(float2*)&out[(size_t)n * DOUT + lane * 2] = acc;
}

// ---------------- launch ----------------
extern "C" void kernel_launch(void* const* d_in, const int* in_sizes, int n_in,
                              void* d_out, int out_size, void* d_ws, size_t ws_size,
                              hipStream_t stream) {
    const float* x       = (const float*)d_in[0];
    const int*   src     = (const int*)  d_in[1];
    const int*   dst     = (const int*)  d_in[2];
    const float* Wself1  = (const float*)d_in[3];
    const float* Wneigh1 = (const float*)d_in[4];
    const float* b1      = (const float*)d_in[5];
    const float* Wself2  = (const float*)d_in[6];
    const float* Wneigh2 = (const float*)d_in[7];
    const float* b2      = (const float*)d_in[8];
    float* out = (float*)d_out;

    char* ws = (char*)d_ws;
    int*      hist   = (int*)     (ws + 0x0000000ull);
    int*      bcur   = (int*)     (ws + 0x00A0000ull);   // [2346] bucket cursors
    int*      rowptr = (int*)     (ws + 0x0140000ull);
    int*      bsums  = (int*)     (ws + 0x01E0000ull);
    float*    bias1  = (float*)   (ws + 0x01E1000ull);
    float*    bias2  = (float*)   (ws + 0x01E2000ull);
    unsigned* ebuf   = (unsigned*)(ws + 0x0200000ull);   // [1.8M] packed (dlow<<16|src)
    bf16*     B1t    = (bf16*)    (ws + 0x0A00000ull);
    bf16*     B2t    = (bf16*)    (ws + 0x0A40000ull);
    bf16*     Abig   = (bf16*)    (ws + 0x0B00000ull);   // [N][512] bf16 (51.2MB)
    bf16*     y      = (bf16*)    (ws + 0x0B00000ull);   // overlays Abig (dead after gemm1)
    bf16*     h      = (bf16*)    (ws + 0x3C00000ull);   // [N][256] bf16 (25.6MB)
    u16*      col    = (u16*)     (ws + 0x5600000ull);   // [1.8M] u16 (3.6MB)

    hipMemsetAsync(hist, 0, NRN * sizeof(int), stream);

    hist_prep_kernel<<<HIST_BLOCKS + PREP_BLOCKS, 256, 0, stream>>>(
        dst, hist, x, Wself1, Wneigh1, b1, Wself2, Wneigh2, b2,
        Abig, B1t, B2t, bias1, bias2);

    const int nb = (NRN + 1023) / 1024;
    scan_blocks<<<nb, 256, 0, stream>>>(hist, rowptr, bsums, NRN);
    scan_sums<<<1, 256, 0, stream>>>(bsums, nb);
    add_offsets<<<(NRN + 255) / 256, 256, 0, stream>>>(rowptr, bsums, bcur, NRN);

    bucket_scatter<<<(RR * EE + 255) / 256, 256, 0, stream>>>(src, dst, rowptr, bcur, ebuf);
    bucket_sort<<<NBK, 256, 0, stream>>>(rowptr, ebuf, col);

    gather1<<<NRN / 4, 256, 0, stream>>>(rowptr, col, Abig);

    gemm1m<<<dim3((NN + 127) / 128, 2), 256, 0, stream>>>(Abig, B1t, bias1, h);
    gemm2m<<<dim3((NN + 127) / 128, 4), 256, 0, stream>>>(h, B2t, bias2, out, y);

    gather2<<<NN / 4, 256, 0, stream>>>(y, rowptr, col, out);
}

// Round 2
// 451.737 us; speedup vs baseline: 1.6379x; 1.6379x over previous
//
#include <hip/hip_runtime.h>
#include <hip/hip_bf16.h>
#include <cstddef>

// RSAGEConv: 2-layer hetero SAGE (mean agg), N=50000, R=3, E=600000, 128->256->128.
// fp32 in/out. CSR gather aggregation + bf16 MFMA GEMMs.
//
// CSR build is a fully deterministic two-level multisplit (NO global atomics):
//  binhist:    110 blocks x 16K edges, LDS hist over 588 bins (r x 256-node range)
//              -> matrix [588][110]
//  binscan:    1 block scans matrix (bin-major) in place -> offset[bin][blk];
//              also emits binbase[589]
//  binscatter: re-read edges, rank via LDS cursors seeded from matrix column,
//              write packed (d&255)<<16|src to block-private ~112B segments.
//              Every 64B line owned by ONE block/XCD/time-window -> no write amp.
//  binsort:    1 block per bin (~3K recs, 26KB LDS): hist(256) -> wave scan ->
//              write rowptr directly -> LDS counting sort -> coalesced u16 col.
//  (deleted: global hist atomics, 150K scan chain, fill, compact, memset)
//
// Scatter history (dur / WRITE_SIZE):
//   r6 fill: per-node cursor atomics, int col      -> 90us / 121MB (12 at/addr, line amp 16x)
//   r11 bucket_scatter: 2346 cursors               -> 353us / 76MB (768 at/addr SERIALIZED ~460ns each)
//   r12 (this): deterministic multisplit           -> predicted ~30us total, ~8MB write
//
// Then: gather1 -> gemm1m (MFMA) -> gemm2m (MFMA) -> gather2 (unchanged).

#define NN 50000
#define RR 3
#define EE 600000
#define DIN 128
#define DHID 256
#define DOUT 128
#define NRN (RR * NN)

#define RANGE 256                    // nodes per bin
#define NRANGE ((NN + RANGE - 1) / RANGE)   // 196
#define NBIN (RR * NRANGE)           // 588
#define EPB 16384                    // edges per multisplit block
#define NBLK ((RR * EE + EPB - 1) / EPB)    // 110
#define MAXB2 4096                   // max records per bin (mean 3072, +18 sigma)

typedef __hip_bfloat16 bf16;
typedef __hip_bfloat162 bf162;
typedef unsigned short u16;
typedef __attribute__((ext_vector_type(8))) short short8;
typedef __attribute__((ext_vector_type(4))) float floatx4;

__device__ __forceinline__ void async_copy16(const void* g, void* l) {
    __builtin_amdgcn_global_load_lds((const __attribute__((address_space(1))) void*)g,
                                     (__attribute__((address_space(3))) void*)l, 16, 0, 0);
}

// ---------------- prep: Abig[:,0:128]=bf16(x); B1t; B2t; bias sums ----------------
#define PREP_A (NN * 64)
#define PREP_B (256 * 512)
#define PREP_C (512 * 256)
#define PREP_D 384
#define PREP_TOTAL (PREP_A + PREP_B + PREP_C + PREP_D)
#define PREP_BLOCKS ((PREP_TOTAL + 255) / 256)

__global__ void prep_kernel(const float* __restrict__ x,
        const float* __restrict__ Ws1, const float* __restrict__ Wn1,
        const float* __restrict__ b1,
        const float* __restrict__ Ws2, const float* __restrict__ Wn2,
        const float* __restrict__ b2,
        bf16* __restrict__ Abig, bf16* __restrict__ B1t, bf16* __restrict__ B2t,
        float* __restrict__ bias1, float* __restrict__ bias2) {
    int idx = blockIdx.x * 256 + threadIdx.x;
    if (idx < PREP_A) {
        int n = idx >> 6, c2 = idx & 63;
        float2 v = *(const float2*)&x[(size_t)n * DIN + c2 * 2];
        bf162 o; o.x = __float2bfloat16(v.x); o.y = __float2bfloat16(v.y);
        *(bf162*)&Abig[(size_t)n * 512 + c2 * 2] = o;
        return;
    }
    idx -= PREP_A;
    if (idx < PREP_B) {
        int n = idx >> 9, k = idx & 511;
        float v;
        if (k < 128) {
            v = Ws1[(size_t)k * 256 + n]
              + Ws1[(size_t)(128 + k) * 256 + n]
              + Ws1[(size_t)(256 + k) * 256 + n];
        } else {
            int q = k - 128; int r = q >> 7; int kk = q & 127;
            v = Wn1[((size_t)r * 128 + kk) * 256 + n];
        }
        B1t[(size_t)n * 512 + k] = __float2bfloat16(v);
        return;
    }
    idx -= PREP_B;
    if (idx < PREP_C) {
        int n = idx >> 8, k = idx & 255;
        float v;
        if (n < 128) {
            v = Ws2[(size_t)k * 128 + n]
              + Ws2[(size_t)(256 + k) * 128 + n]
              + Ws2[(size_t)(512 + k) * 128 + n];
        } else {
            int q = n - 128; int r = q >> 7; int nn = q & 127;
            v = Wn2[((size_t)r * 256 + k) * 128 + nn];
        }
        B2t[(size_t)n * 256 + k] = __float2bfloat16(v);
        return;
    }
    idx -= PREP_C;
    if (idx < PREP_D) {
        if (idx < 256) {
            bias1[idx] = b1[idx] + b1[256 + idx] + b1[512 + idx];
        } else {
            int j = idx - 256;
            bias2[j] = b2[j] + b2[128 + j] + b2[256 + j];
        }
    }
}

// ---------------- multisplit pass 1: per-block LDS histogram over 588 bins ----------------
__global__ __launch_bounds__(256) void binhist(const int* __restrict__ dst,
                                               int* __restrict__ m) {
    __shared__ int lh[NBIN];
    for (int i = threadIdx.x; i < NBIN; i += 256) lh[i] = 0;
    __syncthreads();
    int base = blockIdx.x * EPB;
    int lim = min(EPB, RR * EE - base);
    for (int i = threadIdx.x; i < lim; i += 256) {
        int e = base + i;
        int r = e / EE;
        int d = dst[e];
        atomicAdd(&lh[r * NRANGE + (d >> 8)], 1);
    }
    __syncthreads();
    for (int i = threadIdx.x; i < NBIN; i += 256) m[i * NBLK + blockIdx.x] = lh[i];
}

// ---------------- multisplit pass 2: single-block exclusive scan of [NBIN][NBLK] ----------------
__global__ __launch_bounds__(1024) void binscan(int* __restrict__ m,
                                                int* __restrict__ binbase) {
    __shared__ int wsum[16], woff[16];
    __shared__ int running;
    int t = threadIdx.x, lane = t & 63, wid = t >> 6;
    if (t == 0) running = 0;
    __syncthreads();
    const int total = NBIN * NBLK;
    for (int base = 0; base < total; base += 1024) {
        int idx = base + t;
        int v = (idx < total) ? m[idx] : 0;
        int sc = v;
        #pragma unroll
        for (int d = 1; d < 64; d <<= 1) {
            int tt = __shfl_up(sc, d, 64);
            if (lane >= d) sc += tt;
        }
        if (lane == 63) wsum[wid] = sc;
        __syncthreads();
        if (t == 0) {
            int a = running;
            #pragma unroll
            for (int i = 0; i < 16; ++i) { woff[i] = a; a += wsum[i]; }
            running = a;
        }
        __syncthreads();
        int excl = sc - v + woff[wid];
        if (idx < total) {
            m[idx] = excl;
            if (idx % NBLK == 0) binbase[idx / NBLK] = excl;
        }
        __syncthreads();
    }
    if (t == 0) binbase[NBIN] = RR * EE;
}

// ---------------- multisplit pass 3: rank via LDS cursors, block-private segment writes ----------------
__global__ __launch_bounds__(256) void binscatter(const int* __restrict__ src,
        const int* __restrict__ dst, const int* __restrict__ m,
        unsigned* __restrict__ ebuf) {
    __shared__ int scur[NBIN];
    for (int i = threadIdx.x; i < NBIN; i += 256) scur[i] = m[i * NBLK + blockIdx.x];
    __syncthreads();
    int base = blockIdx.x * EPB;
    int lim = min(EPB, RR * EE - base);
    for (int i = threadIdx.x; i < lim; i += 256) {
        int e = base + i;
        int r = e / EE;
        int d = dst[e];
        int pos = atomicAdd(&scur[r * NRANGE + (d >> 8)], 1);
        ebuf[pos] = ((unsigned)(d & 255) << 16) | (unsigned)src[e];
    }
}

// ---------------- per-bin LDS counting sort -> rowptr + coalesced u16 col ----------------
__global__ __launch_bounds__(256) void binsort(const int* __restrict__ binbase,
        const unsigned* __restrict__ ebuf, u16* __restrict__ col,
        int* __restrict__ rowptr) {
    int b = blockIdx.x;
    int r = b / NRANGE, rb = b - r * NRANGE;
    int node0 = rb * RANGE;
    int nn = min(RANGE, NN - node0);
    int beg = binbase[b], end = binbase[b + 1];
    int cnt = min(end - beg, MAXB2);

    __shared__ unsigned eb[MAXB2];
    __shared__ u16 sb[MAXB2];
    __shared__ int lh[RANGE], lc[RANGE];
    __shared__ int wsum[4], woff[4];

    for (int i = threadIdx.x; i < cnt; i += 256) eb[i] = ebuf[beg + i];
    lh[threadIdx.x] = 0;
    __syncthreads();
    for (int i = threadIdx.x; i < cnt; i += 256) atomicAdd(&lh[eb[i] >> 16], 1);
    __syncthreads();
    {   // exclusive scan of 256 counters (4 waves)
        int t = threadIdx.x, lane = t & 63, wid = t >> 6;
        int v = lh[t];
        int sc = v;
        #pragma unroll
        for (int d = 1; d < 64; d <<= 1) {
            int tt = __shfl_up(sc, d, 64);
            if (lane >= d) sc += tt;
        }
        if (lane == 63) wsum[wid] = sc;
        __syncthreads();
        if (t == 0) {
            int a = 0;
            #pragma unroll
            for (int i = 0; i < 4; ++i) { woff[i] = a; a += wsum[i]; }
        }
        __syncthreads();
        int excl = sc - v + woff[wid];
        lc[t] = excl;
        if (t < nn) rowptr[r * NN + node0 + t] = beg + excl;
        if (t == 0) rowptr[r * NN + node0 + nn] = end;   // dup of next bin's first (same value)
    }
    __syncthreads();
    for (int i = threadIdx.x; i < cnt; i += 256) {
        unsigned e = eb[i];
        int pos = atomicAdd(&lc[e >> 16], 1);
        sb[pos] = (u16)(e & 0xffffu);
    }
    __syncthreads();
    for (int i = threadIdx.x; i < cnt; i += 256) col[beg + i] = sb[i];
}

__device__ __forceinline__ float bflo(unsigned u) { return __uint_as_float(u << 16); }
__device__ __forceinline__ float bfhi(unsigned u) { return __uint_as_float(u & 0xffff0000u); }

// ---------------- gather1: Abig[n][128+128r..] = mean_{s in col[r,n]} bf16x[s] ----------------
__global__ __launch_bounds__(256) void gather1(const int* __restrict__ rowptr,
        const u16* __restrict__ col, bf16* __restrict__ Abig) {
    int g = blockIdx.x * 4 + (threadIdx.x >> 6);   // r*NN + n
    int lane = threadIdx.x & 63;
    int r = g / NN;
    int n = g - r * NN;
    int beg = rowptr[g], end = rowptr[g + 1];
    const unsigned* xb = (const unsigned*)Abig;    // row stride 256 uints
    float acc0 = 0.f, acc1 = 0.f;
    for (int base = beg; base < end; base += 64) {
        int cnt = min(64, end - base);
        int cidx = (lane < cnt) ? (int)col[base + lane] : 0;
        int j = 0;
        for (; j + 8 <= cnt; j += 8) {
            unsigned u0 = xb[(size_t)__shfl(cidx, j,     64) * 256 + lane];
            unsigned u1 = xb[(size_t)__shfl(cidx, j + 1, 64) * 256 + lane];
            unsigned u2 = xb[(size_t)__shfl(cidx, j + 2, 64) * 256 + lane];
            unsigned u3 = xb[(size_t)__shfl(cidx, j + 3, 64) * 256 + lane];
            unsigned u4 = xb[(size_t)__shfl(cidx, j + 4, 64) * 256 + lane];
            unsigned u5 = xb[(size_t)__shfl(cidx, j + 5, 64) * 256 + lane];
            unsigned u6 = xb[(size_t)__shfl(cidx, j + 6, 64) * 256 + lane];
            unsigned u7 = xb[(size_t)__shfl(cidx, j + 7, 64) * 256 + lane];
            acc0 += bflo(u0) + bflo(u1) + bflo(u2) + bflo(u3)
                  + bflo(u4) + bflo(u5) + bflo(u6) + bflo(u7);
            acc1 += bfhi(u0) + bfhi(u1) + bfhi(u2) + bfhi(u3)
                  + bfhi(u4) + bfhi(u5) + bfhi(u6) + bfhi(u7);
        }
        for (; j + 4 <= cnt; j += 4) {
            unsigned u0 = xb[(size_t)__shfl(cidx, j,     64) * 256 + lane];
            unsigned u1 = xb[(size_t)__shfl(cidx, j + 1, 64) * 256 + lane];
            unsigned u2 = xb[(size_t)__shfl(cidx, j + 2, 64) * 256 + lane];
            unsigned u3 = xb[(size_t)__shfl(cidx, j + 3, 64) * 256 + lane];
            acc0 += bflo(u0) + bflo(u1) + bflo(u2) + bflo(u3);
            acc1 += bfhi(u0) + bfhi(u1) + bfhi(u2) + bfhi(u3);
        }
        for (; j < cnt; ++j) {
            unsigned u = xb[(size_t)__shfl(cidx, j, 64) * 256 + lane];
            acc0 += bflo(u);
            acc1 += bfhi(u);
        }
    }
    float inv = 1.0f / fmaxf((float)(end - beg), 1.0f);
    bf162 o;
    o.x = __float2bfloat16(acc0 * inv);
    o.y = __float2bfloat16(acc1 * inv);
    *(bf162*)&Abig[(size_t)n * 512 + 128 + r * 128 + lane * 2] = o;
}

// ---------------- MFMA GEMM 1: Abig[N][512](bf16) x B1t[256][512] -> h bf16 [N][256] ----------------
__global__ __launch_bounds__(256) void gemm1m(const bf16* __restrict__ A,
        const bf16* __restrict__ Bt, const float* __restrict__ bias1,
        bf16* __restrict__ h) {
    __shared__ short As[128 * 32];
    __shared__ short Bs[128 * 32];
    const int t = threadIdx.x;
    const int wv = t >> 6, lane = t & 63;
    const int wr = wv >> 1, wc = wv & 1;
    const int m16 = lane & 15, kg = lane >> 4;
    const int row0 = blockIdx.x * 128;
    const int col0 = blockIdx.y * 128;
    const int ldrow = (t >> 2);
    const int ldk = (t & 3) * 8;
    const int arow0 = min(row0 + ldrow, NN - 1);
    const int arow1 = min(row0 + ldrow + 64, NN - 1);
    const short* Ag0 = (const short*)A + (size_t)arow0 * 512 + ldk;
    const short* Ag1 = (const short*)A + (size_t)arow1 * 512 + ldk;
    const short* Bg = (const short*)Bt + (size_t)(col0 + ldrow) * 512 + ldk;
    short* AsW = &As[(size_t)wv * 512];
    short* BsW = &Bs[(size_t)wv * 512];

    floatx4 acc[4][4] = {};
    for (int kb = 0; kb < 512; kb += 32) {
        async_copy16(Ag0 + kb, AsW);
        async_copy16(Ag1 + kb, AsW + 2048);
        async_copy16(Bg + kb, BsW);
        async_copy16(Bg + kb + (size_t)64 * 512, BsW + 2048);
        __syncthreads();
        short8 a[4], b[4];
        #pragma unroll
        for (int i = 0; i < 4; ++i)
            a[i] = *(const short8*)&As[(wr * 64 + i * 16 + m16) * 32 + kg * 8];
        #pragma unroll
        for (int j = 0; j < 4; ++j)
            b[j] = *(const short8*)&Bs[(wc * 64 + j * 16 + m16) * 32 + kg * 8];
        #pragma unroll
        for (int i = 0; i < 4; ++i)
            #pragma unroll
            for (int j = 0; j < 4; ++j)
                acc[i][j] = __builtin_amdgcn_mfma_f32_16x16x32_bf16(a[i], b[j], acc[i][j], 0, 0, 0);
        __syncthreads();
    }
    #pragma unroll
    for (int j = 0; j < 4; ++j) {
        int c = col0 + wc * 64 + j * 16 + m16;
        float bj = bias1[c];
        #pragma unroll
        for (int i = 0; i < 4; ++i) {
            int rb = row0 + wr * 64 + i * 16 + kg * 4;
            #pragma unroll
            for (int reg = 0; reg < 4; ++reg) {
                int r = rb + reg;
                if (r < NN)
                    h[(size_t)r * DHID + c] = __float2bfloat16(fmaxf(acc[i][j][reg] + bj, 0.f));
            }
        }
    }
}

// ---------------- MFMA GEMM 2: h[N][256](bf16) x B2t[512][256] -> out fp32 [N][128] + y bf16 [3][N][128]
__global__ __launch_bounds__(256) void gemm2m(const bf16* __restrict__ A,
        const bf16* __restrict__ Bt, const float* __restrict__ bias2,
        float* __restrict__ out, bf16* __restrict__ y) {
    __shared__ short As[128 * 32];
    __shared__ short Bs[128 * 32];
    const int t = threadIdx.x;
    const int wv = t >> 6, lane = t & 63;
    const int wr = wv >> 1, wc = wv & 1;
    const int m16 = lane & 15, kg = lane >> 4;
    const int row0 = blockIdx.x * 128;
    const int col0 = blockIdx.y * 128;
    const int ldrow = (t >> 2);
    const int ldk = (t & 3) * 8;
    const int arow0 = min(row0 + ldrow, NN - 1);
    const int arow1 = min(row0 + ldrow + 64, NN - 1);
    const short* Ag0 = (const short*)A + (size_t)arow0 * 256 + ldk;
    const short* Ag1 = (const short*)A + (size_t)arow1 * 256 + ldk;
    const short* Bg = (const short*)Bt + (size_t)(col0 + ldrow) * 256 + ldk;
    short* AsW = &As[(size_t)wv * 512];
    short* BsW = &Bs[(size_t)wv * 512];

    floatx4 acc[4][4] = {};
    for (int kb = 0; kb < 256; kb += 32) {
        async_copy16(Ag0 + kb, AsW);
        async_copy16(Ag1 + kb, AsW + 2048);
        async_copy16(Bg + kb, BsW);
        async_copy16(Bg + kb + (size_t)64 * 256, BsW + 2048);
        __syncthreads();
        short8 a[4], b[4];
        #pragma unroll
        for (int i = 0; i < 4; ++i)
            a[i] = *(const short8*)&As[(wr * 64 + i * 16 + m16) * 32 + kg * 8];
        #pragma unroll
        for (int j = 0; j < 4; ++j)
            b[j] = *(const short8*)&Bs[(wc * 64 + j * 16 + m16) * 32 + kg * 8];
        #pragma unroll
        for (int i = 0; i < 4; ++i)
            #pragma unroll
            for (int j = 0; j < 4; ++j)
                acc[i][j] = __builtin_amdgcn_mfma_f32_16x16x32_bf16(a[i], b[j], acc[i][j], 0, 0, 0);
        __syncthreads();
    }
    if (blockIdx.y == 0) {
        #pragma unroll
        for (int j = 0; j < 4; ++j) {
            int c = wc * 64 + j * 16 + m16;
            float bj = bias2[c];
            #pragma unroll
            for (int i = 0; i < 4; ++i) {
                int rb = row0 + wr * 64 + i * 16 + kg * 4;
                #pragma unroll
                for (int reg = 0; reg < 4; ++reg) {
                    int r = rb + reg;
                    if (r < NN) out[(size_t)r * DOUT + c] = acc[i][j][reg] + bj;
                }
            }
        }
    } else {
        int rel = blockIdx.y - 1;
        bf16* yr = y + (size_t)rel * NN * DOUT;
        #pragma unroll
        for (int j = 0; j < 4; ++j) {
            int c = wc * 64 + j * 16 + m16;
            #pragma unroll
            for (int i = 0; i < 4; ++i) {
                int rb = row0 + wr * 64 + i * 16 + kg * 4;
                #pragma unroll
                for (int reg = 0; reg < 4; ++reg) {
                    int r = rb + reg;
                    if (r < NN) yr[(size_t)r * DOUT + c] = __float2bfloat16(acc[i][j][reg]);
                }
            }
        }
    }
}

// ---------------- gather2: out[n] += sum_r mean_{s in col[r,n]} y[r][s] (unroll-8) ----------------
__global__ __launch_bounds__(256) void gather2(const bf16* __restrict__ y,
        const int* __restrict__ rowptr, const u16* __restrict__ col,
        float* __restrict__ out) {
    int n = blockIdx.x * 4 + (threadIdx.x >> 6);
    int lane = threadIdx.x & 63;
    float2 acc = *(float2*)&out[(size_t)n * DOUT + lane * 2];
    const unsigned* yb = (const unsigned*)y;   // row stride 64 uints
    #pragma unroll
    for (int r = 0; r < RR; ++r) {
        const unsigned* ybr = yb + (size_t)r * NN * 64;
        int g = r * NN + n;
        int beg = rowptr[g], end = rowptr[g + 1];
        float a0 = 0.f, a1 = 0.f;
        for (int base = beg; base < end; base += 64) {
            int cnt = min(64, end - base);
            int cidx = (lane < cnt) ? (int)col[base + lane] : 0;
            int j = 0;
            for (; j + 8 <= cnt; j += 8) {
                unsigned u0 = ybr[(size_t)__shfl(cidx, j,     64) * 64 + lane];
                unsigned u1 = ybr[(size_t)__shfl(cidx, j + 1, 64) * 64 + lane];
                unsigned u2 = ybr[(size_t)__shfl(cidx, j + 2, 64) * 64 + lane];
                unsigned u3 = ybr[(size_t)__shfl(cidx, j + 3, 64) * 64 + lane];
                unsigned u4 = ybr[(size_t)__shfl(cidx, j + 4, 64) * 64 + lane];
                unsigned u5 = ybr[(size_t)__shfl(cidx, j + 5, 64) * 64 + lane];
                unsigned u6 = ybr[(size_t)__shfl(cidx, j + 6, 64) * 64 + lane];
                unsigned u7 = ybr[(size_t)__shfl(cidx, j + 7, 64) * 64 + lane];
                a0 += bflo(u0) + bflo(u1) + bflo(u2) + bflo(u3)
                    + bflo(u4) + bflo(u5) + bflo(u6) + bflo(u7);
                a1 += bfhi(u0) + bfhi(u1) + bfhi(u2) + bfhi(u3)
                    + bfhi(u4) + bfhi(u5) + bfhi(u6) + bfhi(u7);
            }
            for (; j + 4 <= cnt; j += 4) {
                unsigned u0 = ybr[(size_t)__shfl(cidx, j,     64) * 64 + lane];
                unsigned u1 = ybr[(size_t)__shfl(cidx, j + 1, 64) * 64 + lane];
                unsigned u2 = ybr[(size_t)__shfl(cidx, j + 2, 64) * 64 + lane];
                unsigned u3 = ybr[(size_t)__shfl(cidx, j + 3, 64) * 64 + lane];
                a0 += bflo(u0) + bflo(u1) + bflo(u2) + bflo(u3);
                a1 += bfhi(u0) + bfhi(u1) + bfhi(u2) + bfhi(u3);
            }
            for (; j < cnt; ++j) {
                unsigned u = ybr[(size_t)__shfl(cidx, j, 64) * 64 + lane];
                a0 += bflo(u);
                a1 += bfhi(u);
            }
        }
        float inv = 1.0f / fmaxf((float)(end - beg), 1.0f);
        acc.x += a0 * inv;
        acc.y += a1 * inv;
    }
    *(float2*)&out[(size_t)n * DOUT + lane * 2] = acc;
}

// ---------------- launch ----------------
extern "C" void kernel_launch(void* const* d_in, const int* in_sizes, int n_in,
                              void* d_out, int out_size, void* d_ws, size_t ws_size,
                              hipStream_t stream) {
    const float* x       = (const float*)d_in[0];
    const int*   src     = (const int*)  d_in[1];
    const int*   dst     = (const int*)  d_in[2];
    const float* Wself1  = (const float*)d_in[3];
    const float* Wneigh1 = (const float*)d_in[4];
    const float* b1      = (const float*)d_in[5];
    const float* Wself2  = (const float*)d_in[6];
    const float* Wneigh2 = (const float*)d_in[7];
    const float* b2      = (const float*)d_in[8];
    float* out = (float*)d_out;

    char* ws = (char*)d_ws;
    int*      mtx     = (int*)     (ws + 0x0000000ull);   // [588][110] ints (259KB)
    int*      binbase = (int*)     (ws + 0x0060000ull);   // [589]
    int*      rowptr  = (int*)     (ws + 0x0140000ull);   // [NRN+1] (600KB)
    float*    bias1   = (float*)   (ws + 0x01E1000ull);
    float*    bias2   = (float*)   (ws + 0x01E2000ull);
    unsigned* ebuf    = (unsigned*)(ws + 0x0200000ull);   // [1.8M] packed (d&255)<<16|src
    bf16*     B1t     = (bf16*)    (ws + 0x0A00000ull);
    bf16*     B2t     = (bf16*)    (ws + 0x0A40000ull);
    bf16*     Abig    = (bf16*)    (ws + 0x0B00000ull);   // [N][512] bf16 (51.2MB)
    bf16*     y       = (bf16*)    (ws + 0x0B00000ull);   // overlays Abig (dead after gemm1)
    bf16*     h       = (bf16*)    (ws + 0x3C00000ull);   // [N][256] bf16 (25.6MB)
    u16*      col     = (u16*)     (ws + 0x5600000ull);   // [1.8M] u16 (3.6MB)

    prep_kernel<<<PREP_BLOCKS, 256, 0, stream>>>(
        x, Wself1, Wneigh1, b1, Wself2, Wneigh2, b2,
        Abig, B1t, B2t, bias1, bias2);

    binhist<<<NBLK, 256, 0, stream>>>(dst, mtx);
    binscan<<<1, 1024, 0, stream>>>(mtx, binbase);
    binscatter<<<NBLK, 256, 0, stream>>>(src, dst, mtx, ebuf);
    binsort<<<NBIN, 256, 0, stream>>>(binbase, ebuf, col, rowptr);

    gather1<<<NRN / 4, 256, 0, stream>>>(rowptr, col, Abig);

    gemm1m<<<dim3((NN + 127) / 128, 2), 256, 0, stream>>>(Abig, B1t, bias1, h);
    gemm2m<<<dim3((NN + 127) / 128, 4), 256, 0, stream>>>(h, B2t, bias2, out, y);

    gather2<<<NN / 4, 256, 0, stream>>>(y, rowptr, col, out);
}